// Round 2
// baseline (753.499 us; speedup 1.0000x reference)
//
#include <hip/hip_runtime.h>
#include <hip/hip_bf16.h>

// Problem constants
#define Bz 64
#define Nz 512
#define Ez 1024
#define Hz 16
#define DHz 64

static constexpr int MROWS = Bz * Nz;   // 32768
static constexpr int NQKV  = 3 * Ez;    // 3072

typedef __attribute__((ext_vector_type(8))) short bf16x8_t;   // 8 bf16 = 4 VGPRs
typedef __attribute__((ext_vector_type(4))) float f32x4_t;
typedef __attribute__((ext_vector_type(16))) float f32x16_t;
typedef __attribute__((ext_vector_type(4))) unsigned u32x4_t;

union FragU { bf16x8_t h; u32x4_t u; };

__device__ __forceinline__ unsigned short f2bf(float f) {
    union { float f; unsigned u; } v; v.f = f;
    unsigned r = v.u + 0x7FFFu + ((v.u >> 16) & 1u);   // round-to-nearest-even
    return (unsigned short)(r >> 16);
}
__device__ __forceinline__ float bf2f(unsigned short h) {
    union { unsigned u; float f; } v; v.u = ((unsigned)h) << 16;
    return v.f;
}
// pack two non-negative floats to bf16 pair (lo | hi<<16), round-half-up
__device__ __forceinline__ unsigned packbf(float a, float b) {
    union { float f; unsigned u; } x, y; x.f = a; y.f = b;
    return ((x.u + 0x8000u) >> 16) | ((y.u + 0x8000u) & 0xFFFF0000u);
}

// async global->LDS, 16B per lane. LDS dest = wave-uniform base + lane*16.
__device__ __forceinline__ void async16(const unsigned short* g, unsigned short* l) {
    __builtin_amdgcn_global_load_lds(
        (const __attribute__((address_space(1))) void*)g,
        (__attribute__((address_space(3))) void*)l, 16, 0, 0);
}

// LDS-ordering barrier WITHOUT vmcnt drain: drain ds_read queue (so no wave's
// outstanding LDS read can land after another wave's staging overwrite), then
// raw s_barrier. sched_barrier(0) fences reg-only MFMA motion (rule #18).
__device__ __forceinline__ void barrier_lds() {
    asm volatile("s_waitcnt lgkmcnt(0)" ::: "memory");
    __builtin_amdgcn_sched_barrier(0);
    __builtin_amdgcn_s_barrier();
    __builtin_amdgcn_sched_barrier(0);
}

// ---------------------------------------------------------------------------
// Convert fp32 -> bf16 (packed, vectorized)
__global__ void cvt_f32_bf16(const float* __restrict__ in,
                             unsigned short* __restrict__ out, int n4) {
    int id = blockIdx.x * blockDim.x + threadIdx.x;
    int stride = gridDim.x * blockDim.x;
    for (int i = id; i < n4; i += stride) {
        float4 f = ((const float4*)in)[i];
        ushort4 o;
        o.x = f2bf(f.x); o.y = f2bf(f.y); o.z = f2bf(f.z); o.w = f2bf(f.w);
        ((ushort4*)out)[i] = o;
    }
}

// Convert + transpose: in [K][Ncols] fp32 -> out [Ncols][K] bf16.
__global__ __launch_bounds__(256)
void cvt_transpose(const float* __restrict__ in,
                   unsigned short* __restrict__ out,
                   int K, int Ncols) {
    int n  = blockIdx.x * 256 + threadIdx.x;
    int k0 = blockIdx.y * 8;
    bf16x8_t o;
#pragma unroll
    for (int j = 0; j < 8; j++)
        o[j] = (short)f2bf(in[(long)(k0 + j) * Ncols + n]);
    *(bf16x8_t*)&out[(long)n * K + k0] = o;
}

// adj[512][512] int -> bitmask adjm[512][8] u64, self-loops baked in
__global__ void build_adjm(const int* __restrict__ adj,
                           unsigned long long* __restrict__ adjm) {
    int id = blockIdx.x * blockDim.x + threadIdx.x;   // 0..4095
    int n = id >> 3, w = id & 7;
    const int4* r4 = (const int4*)(adj + (long)n * Nz + w * 64);
    unsigned long long m = 0;
#pragma unroll
    for (int c = 0; c < 16; c++) {
        int4 v = r4[c];
        unsigned long long bits =
            (unsigned long long)(v.x != 0) | ((unsigned long long)(v.y != 0) << 1) |
            ((unsigned long long)(v.z != 0) << 2) | ((unsigned long long)(v.w != 0) << 3);
        m |= bits << (c * 4);
    }
    if ((n >> 6) == w) m |= 1ull << (n & 63);
    adjm[id] = m;
}

// ---------------------------------------------------------------------------
// bf16 MFMA GEMM v5: C[M][Ncols] = A[M][K] @ BT[Ncols][K]^T + bias
// 256x256 block tile, BK=64, 512 threads (8 waves, 2Mx4N), 32x32x16 MFMA.
// 2-deep LDS pipeline with COUNTED vmcnt (T3+T4): staging runs 1.5 K-tiles
// ahead; A(t+1) issued in sub-phase A (target buffer consumed in tile t-1),
// B(t+2) issued in sub-phase B into the *current* buffer (its B region was
// fully read in sub-phase A and drained by barrier_lds). End-of-tile wait is
// s_waitcnt vmcnt(4): of the 12 outstanding loads {B(t+1),A(t+1),B(t+2)} the
// oldest 8 (= all of K-tile t+1) complete; B(t+2) stays in flight. vmcnt
// never drains to 0 in the main loop. Raw s_barrier (NOT __syncthreads) so
// the compiler can't reinsert the vmcnt(0) drain (the m97 ~900TF stall).
// XOR-8 chunk swizzle on LDS rows (conflict-free frag reads, pre-swizzled
// global source addresses for the linear global_load_lds destination).
template<bool OUT_BF16>
__global__ __launch_bounds__(512, 2)
void gemm_mfma(const unsigned short* __restrict__ A,
               const unsigned short* __restrict__ BT,
               const float* __restrict__ bias,
               void* __restrict__ C,
               int M, int Ncols, int K) {
    const int tid  = threadIdx.x;
    const int w    = tid >> 6;
    const int lane = tid & 63;
    const int m32  = lane & 31;     // row within 32-tile
    const int kh   = lane >> 5;     // k-half selector
    const int wm   = (w >> 2) * 128;   // wave row base within tile (2 wave-rows)
    const int wn   = (w & 3) * 64;     // wave col base within tile (4 wave-cols)

    // XCD-aware chunked swizzle (both grids are multiples of 8 blocks)
    const int nwg = gridDim.x * gridDim.y;
    const int bid = blockIdx.y * gridDim.x + blockIdx.x;
    const int swz = (bid & 7) * (nwg >> 3) + (bid >> 3);
    const int rowBase = (swz / gridDim.x) * 256;
    const int colBase = (swz % gridDim.x) * 256;

    __shared__ __align__(16) unsigned short Abuf[2][256][64];   // 64 KiB
    __shared__ __align__(16) unsigned short Bbuf[2][256][64];   // 64 KiB

    f32x16_t acc[4][2];
#pragma unroll
    for (int mi = 0; mi < 4; mi++)
#pragma unroll
        for (int n = 0; n < 2; n++)
#pragma unroll
            for (int r = 0; r < 16; r++)
                acc[mi][n][r] = 0.0f;

    // Staging: per wave 4 loads per matrix tile. Load li covers LDS slots
    // s = (w*4+li)*64 + lane (16B each): row r = s>>3, physical chunk p = s&7
    // holds logical chunk c = p ^ (r&7). Source addresses of 8 consecutive
    // lanes permute within one 128B row segment -> coalesced.
    const unsigned short* srcA[4];
    const unsigned short* srcB[4];
#pragma unroll
    for (int li = 0; li < 4; li++) {
        int s = (w * 4 + li) * 64 + lane;
        int r = s >> 3;
        int c = (s & 7) ^ (r & 7);
        srcA[li] = A  + (size_t)(rowBase + r) * K + c * 8;
        srcB[li] = BT + (size_t)(colBase + r) * K + c * 8;
    }
    const int dstOff = w * 2048;       // shorts; + li*512 per load

    const int nt = K >> 6;             // K-tiles of 64 (16 here)
    const int fsw = m32 & 7;           // fragment-read swizzle key

    // ---- prologue: A(0),B(0) -> buf0 ; B(1) -> buf1 ; wait K(0) only ----
#pragma unroll
    for (int li = 0; li < 4; li++)
        async16(srcA[li], (unsigned short*)Abuf[0] + dstOff + li * 512);
#pragma unroll
    for (int li = 0; li < 4; li++)
        async16(srcB[li], (unsigned short*)Bbuf[0] + dstOff + li * 512);
#pragma unroll
    for (int li = 0; li < 4; li++)
        async16(srcB[li] + 64, (unsigned short*)Bbuf[1] + dstOff + li * 512);
    asm volatile("s_waitcnt vmcnt(4)" ::: "memory");   // 12 issued -> K(0) done
    __builtin_amdgcn_sched_barrier(0);
    __builtin_amdgcn_s_barrier();
    __builtin_amdgcn_sched_barrier(0);

    for (int t = 0; t < nt; t++) {
        const int buf = t & 1;
        bf16x8_t af[2][4], bfr[2][4];

        // ================= sub-phase A: row-half 0 =================
        // issue A(t+1) -> other buffer (A region consumed in tile t-1)
        if (t + 1 < nt) {
#pragma unroll
            for (int li = 0; li < 4; li++)
                async16(srcA[li] + (t + 1) * 64,
                        (unsigned short*)Abuf[buf ^ 1] + dstOff + li * 512);
        }
#pragma unroll
        for (int kc = 0; kc < 4; kc++) {
            int p = (kc * 2 + kh) ^ fsw;
#pragma unroll
            for (int n = 0; n < 2; n++)
                bfr[n][kc] = *(const bf16x8_t*)&Bbuf[buf][wn + n * 32 + m32][p * 8];
#pragma unroll
            for (int mi = 0; mi < 2; mi++)
                af[mi][kc] = *(const bf16x8_t*)&Abuf[buf][wm + mi * 32 + m32][p * 8];
        }
        __builtin_amdgcn_s_setprio(1);
#pragma unroll
        for (int kc = 0; kc < 4; kc++)
#pragma unroll
            for (int mi = 0; mi < 2; mi++)
#pragma unroll
                for (int n = 0; n < 2; n++)
                    acc[mi][n] = __builtin_amdgcn_mfma_f32_32x32x16_bf16(
                        af[mi][kc], bfr[n][kc], acc[mi][n], 0, 0, 0);
        __builtin_amdgcn_s_setprio(0);
        barrier_lds();   // B region of buf now fully consumed by ALL waves

        // ================= sub-phase B: row-half 1 =================
        // issue B(t+2) -> SAME buffer's B region (WAR-safe after barrier)
        if (t + 2 < nt) {
#pragma unroll
            for (int li = 0; li < 4; li++)
                async16(srcB[li] + (t + 2) * 64,
                        (unsigned short*)Bbuf[buf] + dstOff + li * 512);
        }
#pragma unroll
        for (int kc = 0; kc < 4; kc++) {
            int p = (kc * 2 + kh) ^ fsw;
#pragma unroll
            for (int mi = 0; mi < 2; mi++)
                af[mi][kc] = *(const bf16x8_t*)&Abuf[buf][wm + 64 + mi * 32 + m32][p * 8];
        }
        __builtin_amdgcn_s_setprio(1);
#pragma unroll
        for (int kc = 0; kc < 4; kc++)
#pragma unroll
            for (int mi = 0; mi < 2; mi++)
#pragma unroll
                for (int n = 0; n < 2; n++)
                    acc[2 + mi][n] = __builtin_amdgcn_mfma_f32_32x32x16_bf16(
                        af[mi][kc], bfr[n][kc], acc[2 + mi][n], 0, 0, 0);
        __builtin_amdgcn_s_setprio(0);

        // end-of-tile wait: complete K(t+1), keep B(t+2) in flight
        if (t + 2 < nt) {
            asm volatile("s_waitcnt vmcnt(4)" ::: "memory");
            barrier_lds();
        } else if (t + 1 < nt) {
            asm volatile("s_waitcnt vmcnt(0)" ::: "memory");   // tail drain
            barrier_lds();
        }
    }

    // epilogue: C/D layout col=lane&31, row=(reg&3)+8*(reg>>2)+4*kh
#pragma unroll
    for (int n = 0; n < 2; n++) {
        int col = colBase + wn + n * 32 + m32;
        float bv = bias[col];
#pragma unroll
        for (int mi = 0; mi < 4; mi++) {
#pragma unroll
            for (int reg = 0; reg < 16; reg++) {
                int row = rowBase + wm + mi * 32 + (reg & 3) + 8 * (reg >> 2) + 4 * kh;
                float v = acc[mi][n][reg] + bv;
                if (OUT_BF16)
                    ((unsigned short*)C)[(size_t)row * Ncols + col] = f2bf(v);
                else
                    ((float*)C)[(size_t)row * Ncols + col] = v;
            }
        }
    }
}

// ---------------------------------------------------------------------------
// MFMA flash attention (unchanged). One block per (b,h); 8 waves, wave w owns
// Q rows [w*64, w*64+64). S^T = K @ Q^T via 16x16x32 MFMA, exp+mask in
// C-layout, shuffle re-layout P -> A-operand, PV MFMA with V staged transposed.
__global__ __launch_bounds__(512, 2)
void attn_mfma(const unsigned short* __restrict__ qkv,       // [32768][3072] bf16
               const unsigned long long* __restrict__ adjm,  // [512][8]
               unsigned short* __restrict__ y)               // [32768][1024] bf16
{
    const int h = blockIdx.x;
    const int b = blockIdx.y;
    const int tid  = threadIdx.x;
    const int lane = tid & 63;
    const int w    = tid >> 6;
    const int l16  = lane & 15;
    const int q    = lane >> 4;

    __shared__ __align__(16) unsigned short Ks[512][64];   // 64 KiB
    __shared__ __align__(16) unsigned short Vt[64][512];   // 64 KiB (V^T)

    const long rowB = (long)b * Nz;
    const unsigned short* base = qkv + rowB * NQKV;

    for (int idx = tid; idx < 4096; idx += 512) {
        int n = idx >> 3, cc = idx & 7;
        *(bf16x8_t*)&Ks[n][(cc ^ (n & 7)) * 8] =
            *(const bf16x8_t*)&base[(long)n * NQKV + Ez + h * DHz + cc * 8];
    }
    {
        int tp = tid & 255, dh = tid >> 8;
        int n0 = tp * 2;
        bf16x8_t va[4], vb[4];
#pragma unroll
        for (int c = 0; c < 4; c++) {
            va[c] = *(const bf16x8_t*)&base[(long)n0 * NQKV + 2 * Ez + h * DHz + dh * 32 + c * 8];
            vb[c] = *(const bf16x8_t*)&base[(long)(n0 + 1) * NQKV + 2 * Ez + h * DHz + dh * 32 + c * 8];
        }
        unsigned short* vt = &Vt[0][0];
#pragma unroll
        for (int dd = 0; dd < 32; dd++) {
            int d = dh * 32 + dd;
            unsigned lo = (unsigned)(unsigned short)va[dd >> 3][dd & 7];
            unsigned hi = (unsigned)(unsigned short)vb[dd >> 3][dd & 7];
            int cp = (n0 >> 3) ^ (d & 7);
            *(unsigned*)&vt[d * 512 + cp * 8 + (n0 & 7)] = lo | (hi << 16);
        }
    }
    FragU qf[4][2];
#pragma unroll
    for (int mt = 0; mt < 4; mt++)
#pragma unroll
        for (int kc = 0; kc < 2; kc++)
            qf[mt][kc].h = *(const bf16x8_t*)&base[(long)(w * 64 + mt * 16 + l16) * NQKV
                                                   + h * DHz + kc * 32 + q * 8];
    __syncthreads();

    f32x4_t oacc[4][4];
#pragma unroll
    for (int mt = 0; mt < 4; mt++)
#pragma unroll
        for (int dt = 0; dt < 4; dt++) {
            f32x4_t z = {0.0f, 0.0f, 0.0f, 0.0f};
            oacc[mt][dt] = z;
        }
    float rsum[4] = {0.0f, 0.0f, 0.0f, 0.0f};
    unsigned long long wm[4];

    for (int ct = 0; ct < 16; ct++) {
        const int j0 = ct * 32;
        if ((ct & 1) == 0) {
#pragma unroll
            for (int mt = 0; mt < 4; mt++)
                wm[mt] = adjm[(size_t)(w * 64 + mt * 16 + l16) * 8 + (ct >> 1)];
        }
        bf16x8_t kf[2][2];
#pragma unroll
        for (int jt = 0; jt < 2; jt++)
#pragma unroll
            for (int kc = 0; kc < 2; kc++)
                kf[jt][kc] = *(const bf16x8_t*)
                    &Ks[j0 + jt * 16 + l16][((kc * 4 + q) ^ (l16 & 7)) * 8];

        f32x4_t tacc[2][4];
#pragma unroll
        for (int jt = 0; jt < 2; jt++)
#pragma unroll
            for (int mt = 0; mt < 4; mt++) {
                f32x4_t z = {0.0f, 0.0f, 0.0f, 0.0f};
                z = __builtin_amdgcn_mfma_f32_16x16x32_bf16(kf[jt][0], qf[mt][0].h, z, 0, 0, 0);
                tacc[jt][mt] = __builtin_amdgcn_mfma_f32_16x16x32_bf16(kf[jt][1], qf[mt][1].h, z, 0, 0, 0);
            }

        unsigned pk[2][4][2];
#pragma unroll
        for (int jt = 0; jt < 2; jt++)
#pragma unroll
            for (int mt = 0; mt < 4; mt++) {
                float e[4];
#pragma unroll
                for (int r = 0; r < 4; r++) {
                    int jrel = (ct & 1) * 32 + jt * 16 + q * 4 + r;
                    bool bit = (wm[mt] >> jrel) & 1ull;
                    float ev = bit ? __expf(tacc[jt][mt][r] * 0.125f) : 0.0f;
                    e[r] = ev;
                    rsum[mt] += ev;
                }
                pk[jt][mt][0] = packbf(e[0], e[1]);
                pk[jt][mt][1] = packbf(e[2], e[3]);
            }

        bf16x8_t vf[4];
#pragma unroll
        for (int dt = 0; dt < 4; dt++) {
            int d = dt * 16 + l16;
            int cp = (ct * 4 + q) ^ (l16 & 7);
            vf[dt] = *(const bf16x8_t*)&(&Vt[0][0])[d * 512 + cp * 8];
        }

#pragma unroll
        for (int mt = 0; mt < 4; mt++) {
            FragU pf;
#pragma unroll
            for (int p = 0; p < 4; p++) {
                int srcl = ((lane & 16) << 1) | ((p & 2) << 3) | l16;
                unsigned a0 = (unsigned)__shfl((int)pk[0][mt][p & 1], srcl);
                unsigned a1 = (unsigned)__shfl((int)pk[1][mt][p & 1], srcl);
                pf.u[p] = (lane & 32) ? a1 : a0;
            }
#pragma unroll
            for (int dt = 0; dt < 4; dt++)
                oacc[mt][dt] = __builtin_amdgcn_mfma_f32_16x16x32_bf16(
                    pf.h, vf[dt], oacc[mt][dt], 0, 0, 0);
        }
    }

#pragma unroll
    for (int mt = 0; mt < 4; mt++) {
        float s = rsum[mt];
        s += __shfl_xor(s, 16);
        s += __shfl_xor(s, 32);
#pragma unroll
        for (int r = 0; r < 4; r++) {
            float rs = __shfl(s, (lane & 48) | (q * 4) | r);
            float inv = 1.0f / rs;
            int row = w * 64 + mt * 16 + q * 4 + r;
#pragma unroll
            for (int dt = 0; dt < 4; dt++)
                y[(rowB + row) * Ez + h * DHz + dt * 16 + l16] =
                    f2bf(oacc[mt][dt][r] * inv);
        }
    }
}

// ---------------------------------------------------------------------------
extern "C" void kernel_launch(void* const* d_in, const int* in_sizes, int n_in,
                              void* d_out, int out_size, void* d_ws, size_t ws_size,
                              hipStream_t stream) {
    const float* x     = (const float*)d_in[0];
    const float* Wqkv  = (const float*)d_in[1];
    const float* bqkv  = (const float*)d_in[2];
    const float* Wproj = (const float*)d_in[3];
    const float* bproj = (const float*)d_in[4];
    const int*   adj   = (const int*)d_in[5];
    float* out = (float*)d_out;

    char* ws = (char*)d_ws;
    unsigned short* xb     = (unsigned short*)(ws);                 // 67 MB (also yb)
    unsigned short* qkv    = (unsigned short*)(ws + 67108864);      // 201 MB
    unsigned short* WqkvT  = (unsigned short*)(ws + 268435456);     // 6 MB
    unsigned short* WprojT = (unsigned short*)(ws + 274726912);     // 2 MB
    unsigned long long* adjm = (unsigned long long*)(ws + 276824064); // 32 KB
    unsigned short* yb = xb;  // reuse: xb consumed by gemm1 before attn writes yb

    // 1. casts / transposes / adjacency bitmask
    cvt_f32_bf16<<<8192, 256, 0, stream>>>(x, xb, (Bz * Nz * Ez) / 4);
    cvt_transpose<<<dim3(NQKV / 256, Ez / 8), 256, 0, stream>>>(Wqkv, WqkvT, Ez, NQKV);
    cvt_transpose<<<dim3(Ez / 256, Ez / 8), 256, 0, stream>>>(Wproj, WprojT, Ez, Ez);
    build_adjm<<<16, 256, 0, stream>>>(adj, adjm);

    // 2. QKV projection: qkv = xb @ Wqkv + bqkv (bf16 out), 256x256 tiles
    gemm_mfma<true><<<dim3(NQKV / 256, MROWS / 256), 512, 0, stream>>>(
        xb, WqkvT, bqkv, qkv, MROWS, NQKV, Ez);

    // 3. MFMA flash attention
    attn_mfma<<<dim3(Hz, Bz), 512, 0, stream>>>(qkv, adjm, yb);

    // 4. output projection: out = yb @ Wproj + bproj (fp32 out)
    gemm_mfma<false><<<dim3(Ez / 256, MROWS / 256), 512, 0, stream>>>(
        yb, WprojT, bproj, out, MROWS, Ez, Ez);
}

// Round 4
// 743.315 us; speedup vs baseline: 1.0137x; 1.0137x over previous
//
#include <hip/hip_runtime.h>
#include <hip/hip_bf16.h>

// Problem constants
#define Bz 64
#define Nz 512
#define Ez 1024
#define Hz 16
#define DHz 64

static constexpr int MROWS = Bz * Nz;   // 32768
static constexpr int NQKV  = 3 * Ez;    // 3072

typedef __attribute__((ext_vector_type(8))) short bf16x8_t;   // 8 bf16 = 4 VGPRs
typedef __attribute__((ext_vector_type(4))) float f32x4_t;
typedef __attribute__((ext_vector_type(16))) float f32x16_t;
typedef __attribute__((ext_vector_type(4))) unsigned u32x4_t;

union FragU { bf16x8_t h; u32x4_t u; };

__device__ __forceinline__ unsigned short f2bf(float f) {
    union { float f; unsigned u; } v; v.f = f;
    unsigned r = v.u + 0x7FFFu + ((v.u >> 16) & 1u);   // round-to-nearest-even
    return (unsigned short)(r >> 16);
}
__device__ __forceinline__ float bf2f(unsigned short h) {
    union { unsigned u; float f; } v; v.u = ((unsigned)h) << 16;
    return v.f;
}
// pack two non-negative floats to bf16 pair (lo | hi<<16), round-half-up
__device__ __forceinline__ unsigned packbf(float a, float b) {
    union { float f; unsigned u; } x, y; x.f = a; y.f = b;
    return ((x.u + 0x8000u) >> 16) | ((y.u + 0x8000u) & 0xFFFF0000u);
}

// async global->LDS, 16B per lane. LDS dest = wave-uniform base + lane*16.
__device__ __forceinline__ void async16(const unsigned short* g, unsigned short* l) {
    __builtin_amdgcn_global_load_lds(
        (const __attribute__((address_space(1))) void*)g,
        (__attribute__((address_space(3))) void*)l, 16, 0, 0);
}

#define MFMA32(a, b, c) __builtin_amdgcn_mfma_f32_32x32x16_bf16(a, b, c, 0, 0, 0)

// ---------------------------------------------------------------------------
// Convert fp32 -> bf16 (packed, vectorized)
__global__ void cvt_f32_bf16(const float* __restrict__ in,
                             unsigned short* __restrict__ out, int n4) {
    int id = blockIdx.x * blockDim.x + threadIdx.x;
    int stride = gridDim.x * blockDim.x;
    for (int i = id; i < n4; i += stride) {
        float4 f = ((const float4*)in)[i];
        ushort4 o;
        o.x = f2bf(f.x); o.y = f2bf(f.y); o.z = f2bf(f.z); o.w = f2bf(f.w);
        ((ushort4*)out)[i] = o;
    }
}

// Convert + transpose: in [K][Ncols] fp32 -> out [Ncols][K] bf16.
__global__ __launch_bounds__(256)
void cvt_transpose(const float* __restrict__ in,
                   unsigned short* __restrict__ out,
                   int K, int Ncols) {
    int n  = blockIdx.x * 256 + threadIdx.x;
    int k0 = blockIdx.y * 8;
    bf16x8_t o;
#pragma unroll
    for (int j = 0; j < 8; j++)
        o[j] = (short)f2bf(in[(long)(k0 + j) * Ncols + n]);
    *(bf16x8_t*)&out[(long)n * K + k0] = o;
}

// adj[512][512] int -> bitmask adjm[512][8] u64, self-loops baked in
__global__ void build_adjm(const int* __restrict__ adj,
                           unsigned long long* __restrict__ adjm) {
    int id = blockIdx.x * blockDim.x + threadIdx.x;   // 0..4095
    int n = id >> 3, w = id & 7;
    const int4* r4 = (const int4*)(adj + (long)n * Nz + w * 64);
    unsigned long long m = 0;
#pragma unroll
    for (int c = 0; c < 16; c++) {
        int4 v = r4[c];
        unsigned long long bits =
            (unsigned long long)(v.x != 0) | ((unsigned long long)(v.y != 0) << 1) |
            ((unsigned long long)(v.z != 0) << 2) | ((unsigned long long)(v.w != 0) << 3);
        m |= bits << (c * 4);
    }
    if ((n >> 6) == w) m |= 1ull << (n & 63);
    adjm[id] = m;
}

// ---------------------------------------------------------------------------
// bf16 MFMA GEMM v6: 8-phase fine-interleave port of the verified 256x256
// template (m201 cadence). 256x256 tile, BK=64, 512 threads (8 waves, 2Mx4N),
// 32x32x16 MFMA, 4 phases per K-tile.
//
// LDS half-tiles split along K: X-K0 = 256 rows x K-cols[0:32), X-K1 = [32:64).
// Each half stored packed as [128 phys rows][64 shorts] (two logical rows per
// phys row) with an XOR-granule swizzle: phys slot (R, g) holds logical
// (row = 2R + (lg>>2), colgranule = lg&3) where lg = g ^ (R&7). Stage source
// addresses are pre-swizzled (rule 21: linear LDS dest for global_load_lds,
// inverse-swizzled source, swizzled read — same involution).
//
// Per phase p (kc = p): {6 ds_read_b128 (4 A-frags + 2 B-frags), stage exactly
// one half-tile (2 global_load_lds), s_barrier, lgkmcnt(0), setprio(1),
// 8 MFMA, setprio(0), [counted vmcnt on p1/p3], s_barrier}.
// Stage schedule (tile t): p0: A-K1(t+1); p1: B-K1(t+1); p2: A-K0(t+2)
// (slot A-K0(t) retired end p1); p3: B-K0(t+2). Every half lands 6 phases
// before use. Steady-state waits: vmcnt(8) at end of p1 and p3 — the oldest
// 4 completed loads are exactly the 2 half-tiles the next 2 phases read;
// never drains below 8 in the main loop (tails: 0 / 4 exact).
template<bool OUT_BF16>
__global__ __launch_bounds__(512, 2)
void gemm_mfma(const unsigned short* __restrict__ A,
               const unsigned short* __restrict__ BT,
               const float* __restrict__ bias,
               void* __restrict__ C,
               int M, int Ncols, int K) {
    const int tid  = threadIdx.x;
    const int w    = tid >> 6;
    const int lane = tid & 63;
    const int m32  = lane & 31;
    const int kh   = lane >> 5;
    const int wm   = (w >> 2) * 128;   // wave row base (2 wave-rows)
    const int wn   = (w & 3) * 64;     // wave col base (4 wave-cols)

    // XCD-aware chunked swizzle (both grids are multiples of 8 blocks)
    const int nwg = gridDim.x * gridDim.y;
    const int bid = blockIdx.y * gridDim.x + blockIdx.x;
    const int swz = (bid & 7) * (nwg >> 3) + (bid >> 3);
    const int rowBase = (swz / gridDim.x) * 256;
    const int colBase = (swz % gridDim.x) * 256;

    __shared__ __align__(16) unsigned short Ah[2][2][128][64];   // 64 KiB
    __shared__ __align__(16) unsigned short Bh[2][2][128][64];   // 64 KiB

    f32x16_t acc[4][2];
#pragma unroll
    for (int mi = 0; mi < 4; mi++)
#pragma unroll
        for (int n = 0; n < 2; n++)
#pragma unroll
            for (int r = 0; r < 16; r++)
                acc[mi][n][r] = 0.0f;

    // Stage source precompute. Load l covers slots s = l*512 + tid:
    // R = s>>3, g = s&7, lg = g^(R&7) -> global row 2R+(lg>>2), col (lg&3)*8.
    // 8 consecutive lanes cover rows {2R,2R+1} x 64B each -> coalesced.
    const unsigned short* sA[2];
    const unsigned short* sB[2];
#pragma unroll
    for (int l = 0; l < 2; l++) {
        int s = l * 512 + tid;
        int R = s >> 3, g = s & 7;
        int lg = g ^ (R & 7);
        int grow = 2 * R + (lg >> 2);
        int gc8 = (lg & 3) * 8;
        sA[l] = A  + (size_t)(rowBase + grow) * K + gc8;
        sB[l] = BT + (size_t)(colBase + grow) * K + gc8;
    }
    const int dst0 = w * 512;   // shorts; load l adds l*4096

#define STAGE(src, dst, tt, half) do {                                   \
        unsigned short* d_ = &(dst)[0][0];                               \
        async16((src)[0] + (size_t)(tt) * 64 + (half) * 32, d_ + dst0);  \
        async16((src)[1] + (size_t)(tt) * 64 + (half) * 32, d_ + 4096 + dst0); \
    } while (0)

    // Fragment read precompute: row = base + m32 -> R = base/2 + (m32>>1);
    // base/2 is 0 mod 8, so XOR key = (m32>>1)&7 for both A and B; within-pair
    // lg = (m32&1)*4 + kc'*2 + kh.
    const int Ra  = wm / 2 + (m32 >> 1);
    const int Rb  = wn / 2 + (m32 >> 1);
    const int key = (m32 >> 1) & 7;
    const int lgb = (m32 & 1) * 4 + kh;

    const int nt = K >> 6;   // 16

    // ---- prologue: tile0 (4 halves) + tile1 K0 halves; wait K0(0) ----
    STAGE(sA, Ah[0][0], 0, 0);
    STAGE(sB, Bh[0][0], 0, 0);
    STAGE(sA, Ah[0][1], 0, 1);
    STAGE(sB, Bh[0][1], 0, 1);
    STAGE(sA, Ah[1][0], 1, 0);
    STAGE(sB, Bh[1][0], 1, 0);
    asm volatile("s_waitcnt vmcnt(8)" ::: "memory");
    __builtin_amdgcn_sched_barrier(0);
    __builtin_amdgcn_s_barrier();
    __builtin_amdgcn_sched_barrier(0);

    for (int t = 0; t < nt; ++t) {
        const int buf = t & 1;
        const unsigned short *Ab, *Bb;
        bf16x8_t a0, a1, a2, a3, b0, b1;
        int gp8;

#define PHASE_READS()                                                    \
        a0 = *(const bf16x8_t*)(Ab + (Ra +  0) * 64 + gp8);              \
        a1 = *(const bf16x8_t*)(Ab + (Ra + 16) * 64 + gp8);              \
        a2 = *(const bf16x8_t*)(Ab + (Ra + 32) * 64 + gp8);              \
        a3 = *(const bf16x8_t*)(Ab + (Ra + 48) * 64 + gp8);              \
        b0 = *(const bf16x8_t*)(Bb + (Rb +  0) * 64 + gp8);              \
        b1 = *(const bf16x8_t*)(Bb + (Rb + 16) * 64 + gp8)

#define PHASE_MFMA()                                                     \
        __builtin_amdgcn_s_barrier();                                    \
        asm volatile("s_waitcnt lgkmcnt(0)" ::: "memory");               \
        __builtin_amdgcn_sched_barrier(0);                               \
        __builtin_amdgcn_s_setprio(1);                                   \
        acc[0][0] = MFMA32(a0, b0, acc[0][0]);                           \
        acc[0][1] = MFMA32(a0, b1, acc[0][1]);                           \
        acc[1][0] = MFMA32(a1, b0, acc[1][0]);                           \
        acc[1][1] = MFMA32(a1, b1, acc[1][1]);                           \
        acc[2][0] = MFMA32(a2, b0, acc[2][0]);                           \
        acc[2][1] = MFMA32(a2, b1, acc[2][1]);                           \
        acc[3][0] = MFMA32(a3, b0, acc[3][0]);                           \
        acc[3][1] = MFMA32(a3, b1, acc[3][1]);                           \
        __builtin_amdgcn_s_setprio(0)

#define PHASE_CLOSE()                                                    \
        __builtin_amdgcn_sched_barrier(0);                               \
        __builtin_amdgcn_s_barrier();                                    \
        __builtin_amdgcn_sched_barrier(0)

        // ---- phase 0: half0, kc'=0 ; stage A-K1(t+1) ----
        Ab = &Ah[buf][0][0][0]; Bb = &Bh[buf][0][0][0];
        gp8 = ((lgb + 0) ^ key) * 8;
        PHASE_READS();
        if (t + 1 < nt) STAGE(sA, Ah[buf ^ 1][1], t + 1, 1);
        PHASE_MFMA();
        PHASE_CLOSE();

        // ---- phase 1: half0, kc'=1 ; stage B-K1(t+1) ; wait ----
        gp8 = ((lgb + 2) ^ key) * 8;
        PHASE_READS();
        if (t + 1 < nt) STAGE(sB, Bh[buf ^ 1][1], t + 1, 1);
        PHASE_MFMA();
        if (t < nt - 1) { asm volatile("s_waitcnt vmcnt(8)" ::: "memory"); }
        else            { asm volatile("s_waitcnt vmcnt(0)" ::: "memory"); }
        PHASE_CLOSE();

        // ---- phase 2: half1, kc'=0 ; stage A-K0(t+2) ----
        Ab = &Ah[buf][1][0][0]; Bb = &Bh[buf][1][0][0];
        gp8 = ((lgb + 0) ^ key) * 8;
        PHASE_READS();
        if (t + 2 < nt) STAGE(sA, Ah[buf][0], t + 2, 0);
        PHASE_MFMA();
        PHASE_CLOSE();

        // ---- phase 3: half1, kc'=1 ; stage B-K0(t+2) ; wait ----
        gp8 = ((lgb + 2) ^ key) * 8;
        PHASE_READS();
        if (t + 2 < nt) STAGE(sB, Bh[buf][0], t + 2, 0);
        PHASE_MFMA();
        if (t < nt - 2)       { asm volatile("s_waitcnt vmcnt(8)" ::: "memory"); }
        else if (t == nt - 2) { asm volatile("s_waitcnt vmcnt(4)" ::: "memory"); }
        PHASE_CLOSE();
    }
#undef PHASE_READS
#undef PHASE_MFMA
#undef PHASE_CLOSE
#undef STAGE

    // epilogue: C/D layout col=lane&31, row=(reg&3)+8*(reg>>2)+4*kh
#pragma unroll
    for (int n = 0; n < 2; n++) {
        int col = colBase + wn + n * 32 + m32;
        float bv = bias[col];
#pragma unroll
        for (int mi = 0; mi < 4; mi++) {
#pragma unroll
            for (int reg = 0; reg < 16; reg++) {
                int row = rowBase + wm + mi * 32 + (reg & 3) + 8 * (reg >> 2) + 4 * kh;
                float v = acc[mi][n][reg] + bv;
                if (OUT_BF16)
                    ((unsigned short*)C)[(size_t)row * Ncols + col] = f2bf(v);
                else
                    ((float*)C)[(size_t)row * Ncols + col] = v;
            }
        }
    }
}

// ---------------------------------------------------------------------------
// MFMA flash attention (unchanged). One block per (b,h); 8 waves, wave w owns
// Q rows [w*64, w*64+64). S^T = K @ Q^T via 16x16x32 MFMA, exp+mask in
// C-layout, shuffle re-layout P -> A-operand, PV MFMA with V staged transposed.
__global__ __launch_bounds__(512, 2)
void attn_mfma(const unsigned short* __restrict__ qkv,       // [32768][3072] bf16
               const unsigned long long* __restrict__ adjm,  // [512][8]
               unsigned short* __restrict__ y)               // [32768][1024] bf16
{
    const int h = blockIdx.x;
    const int b = blockIdx.y;
    const int tid  = threadIdx.x;
    const int lane = tid & 63;
    const int w    = tid >> 6;
    const int l16  = lane & 15;
    const int q    = lane >> 4;

    __shared__ __align__(16) unsigned short Ks[512][64];   // 64 KiB
    __shared__ __align__(16) unsigned short Vt[64][512];   // 64 KiB (V^T)

    const long rowB = (long)b * Nz;
    const unsigned short* base = qkv + rowB * NQKV;

    for (int idx = tid; idx < 4096; idx += 512) {
        int n = idx >> 3, cc = idx & 7;
        *(bf16x8_t*)&Ks[n][(cc ^ (n & 7)) * 8] =
            *(const bf16x8_t*)&base[(long)n * NQKV + Ez + h * DHz + cc * 8];
    }
    {
        int tp = tid & 255, dh = tid >> 8;
        int n0 = tp * 2;
        bf16x8_t va[4], vb[4];
#pragma unroll
        for (int c = 0; c < 4; c++) {
            va[c] = *(const bf16x8_t*)&base[(long)n0 * NQKV + 2 * Ez + h * DHz + dh * 32 + c * 8];
            vb[c] = *(const bf16x8_t*)&base[(long)(n0 + 1) * NQKV + 2 * Ez + h * DHz + dh * 32 + c * 8];
        }
        unsigned short* vt = &Vt[0][0];
#pragma unroll
        for (int dd = 0; dd < 32; dd++) {
            int d = dh * 32 + dd;
            unsigned lo = (unsigned)(unsigned short)va[dd >> 3][dd & 7];
            unsigned hi = (unsigned)(unsigned short)vb[dd >> 3][dd & 7];
            int cp = (n0 >> 3) ^ (d & 7);
            *(unsigned*)&vt[d * 512 + cp * 8 + (n0 & 7)] = lo | (hi << 16);
        }
    }
    FragU qf[4][2];
#pragma unroll
    for (int mt = 0; mt < 4; mt++)
#pragma unroll
        for (int kc = 0; kc < 2; kc++)
            qf[mt][kc].h = *(const bf16x8_t*)&base[(long)(w * 64 + mt * 16 + l16) * NQKV
                                                   + h * DHz + kc * 32 + q * 8];
    __syncthreads();

    f32x4_t oacc[4][4];
#pragma unroll
    for (int mt = 0; mt < 4; mt++)
#pragma unroll
        for (int dt = 0; dt < 4; dt++) {
            f32x4_t z = {0.0f, 0.0f, 0.0f, 0.0f};
            oacc[mt][dt] = z;
        }
    float rsum[4] = {0.0f, 0.0f, 0.0f, 0.0f};
    unsigned long long wm[4];

    for (int ct = 0; ct < 16; ct++) {
        const int j0 = ct * 32;
        if ((ct & 1) == 0) {
#pragma unroll
            for (int mt = 0; mt < 4; mt++)
                wm[mt] = adjm[(size_t)(w * 64 + mt * 16 + l16) * 8 + (ct >> 1)];
        }
        bf16x8_t kf[2][2];
#pragma unroll
        for (int jt = 0; jt < 2; jt++)
#pragma unroll
            for (int kc = 0; kc < 2; kc++)
                kf[jt][kc] = *(const bf16x8_t*)
                    &Ks[j0 + jt * 16 + l16][((kc * 4 + q) ^ (l16 & 7)) * 8];

        f32x4_t tacc[2][4];
#pragma unroll
        for (int jt = 0; jt < 2; jt++)
#pragma unroll
            for (int mt = 0; mt < 4; mt++) {
                f32x4_t z = {0.0f, 0.0f, 0.0f, 0.0f};
                z = __builtin_amdgcn_mfma_f32_16x16x32_bf16(kf[jt][0], qf[mt][0].h, z, 0, 0, 0);
                tacc[jt][mt] = __builtin_amdgcn_mfma_f32_16x16x32_bf16(kf[jt][1], qf[mt][1].h, z, 0, 0, 0);
            }

        unsigned pk[2][4][2];
#pragma unroll
        for (int jt = 0; jt < 2; jt++)
#pragma unroll
            for (int mt = 0; mt < 4; mt++) {
                float e[4];
#pragma unroll
                for (int r = 0; r < 4; r++) {
                    int jrel = (ct & 1) * 32 + jt * 16 + q * 4 + r;
                    bool bit = (wm[mt] >> jrel) & 1ull;
                    float ev = bit ? __expf(tacc[jt][mt][r] * 0.125f) : 0.0f;
                    e[r] = ev;
                    rsum[mt] += ev;
                }
                pk[jt][mt][0] = packbf(e[0], e[1]);
                pk[jt][mt][1] = packbf(e[2], e[3]);
            }

        bf16x8_t vf[4];
#pragma unroll
        for (int dt = 0; dt < 4; dt++) {
            int d = dt * 16 + l16;
            int cp = (ct * 4 + q) ^ (l16 & 7);
            vf[dt] = *(const bf16x8_t*)&(&Vt[0][0])[d * 512 + cp * 8];
        }

#pragma unroll
        for (int mt = 0; mt < 4; mt++) {
            FragU pf;
#pragma unroll
            for (int p = 0; p < 4; p++) {
                int srcl = ((lane & 16) << 1) | ((p & 2) << 3) | l16;
                unsigned a0 = (unsigned)__shfl((int)pk[0][mt][p & 1], srcl);
                unsigned a1 = (unsigned)__shfl((int)pk[1][mt][p & 1], srcl);
                pf.u[p] = (lane & 32) ? a1 : a0;
            }
#pragma unroll
            for (int dt = 0; dt < 4; dt++)
                oacc[mt][dt] = __builtin_amdgcn_mfma_f32_16x16x32_bf16(
                    pf.h, vf[dt], oacc[mt][dt], 0, 0, 0);
        }
    }

#pragma unroll
    for (int mt = 0; mt < 4; mt++) {
        float s = rsum[mt];
        s += __shfl_xor(s, 16);
        s += __shfl_xor(s, 32);
#pragma unroll
        for (int r = 0; r < 4; r++) {
            float rs = __shfl(s, (lane & 48) | (q * 4) | r);
            float inv = 1.0f / rs;
            int row = w * 64 + mt * 16 + q * 4 + r;
#pragma unroll
            for (int dt = 0; dt < 4; dt++)
                y[(rowB + row) * Ez + h * DHz + dt * 16 + l16] =
                    f2bf(oacc[mt][dt][r] * inv);
        }
    }
}

// ---------------------------------------------------------------------------
extern "C" void kernel_launch(void* const* d_in, const int* in_sizes, int n_in,
                              void* d_out, int out_size, void* d_ws, size_t ws_size,
                              hipStream_t stream) {
    const float* x     = (const float*)d_in[0];
    const float* Wqkv  = (const float*)d_in[1];
    const float* bqkv  = (const float*)d_in[2];
    const float* Wproj = (const float*)d_in[3];
    const float* bproj = (const float*)d_in[4];
    const int*   adj   = (const int*)d_in[5];
    float* out = (float*)d_out;

    char* ws = (char*)d_ws;
    unsigned short* xb     = (unsigned short*)(ws);                 // 67 MB (also yb)
    unsigned short* qkv    = (unsigned short*)(ws + 67108864);      // 201 MB
    unsigned short* WqkvT  = (unsigned short*)(ws + 268435456);     // 6 MB
    unsigned short* WprojT = (unsigned short*)(ws + 274726912);     // 2 MB
    unsigned long long* adjm = (unsigned long long*)(ws + 276824064); // 32 KB
    unsigned short* yb = xb;  // reuse: xb consumed by gemm1 before attn writes yb

    // 1. casts / transposes / adjacency bitmask
    cvt_f32_bf16<<<8192, 256, 0, stream>>>(x, xb, (Bz * Nz * Ez) / 4);
    cvt_transpose<<<dim3(NQKV / 256, Ez / 8), 256, 0, stream>>>(Wqkv, WqkvT, Ez, NQKV);
    cvt_transpose<<<dim3(Ez / 256, Ez / 8), 256, 0, stream>>>(Wproj, WprojT, Ez, Ez);
    build_adjm<<<16, 256, 0, stream>>>(adj, adjm);

    // 2. QKV projection: qkv = xb @ Wqkv + bqkv (bf16 out), 256x256 tiles
    gemm_mfma<true><<<dim3(NQKV / 256, MROWS / 256), 512, 0, stream>>>(
        xb, WqkvT, bqkv, qkv, MROWS, NQKV, Ez);

    // 3. MFMA flash attention
    attn_mfma<<<dim3(Hz, Bz), 512, 0, stream>>>(qkv, adjm, yb);

    // 4. output projection: out = yb @ Wproj + bproj (fp32 out)
    gemm_mfma<false><<<dim3(Ez / 256, MROWS / 256), 512, 0, stream>>>(
        yb, WprojT, bproj, out, MROWS, Ez, Ez);
}